// Round 1
// baseline (520.473 us; speedup 1.0000x reference)
//
#include <hip/hip_runtime.h>
#include <math.h>

#define BB 8
#define CC 64
#define NN 2048
#define KK 20
#define OO 128
#define M_TOT 327680.0f   // B*N*K

// ---------------------------------------------------------------------------
// K0: xx[b][j] = sum_c x[b][c][j]^2 in fp64 (exact: fp32*fp32 is exact in f64)
// ---------------------------------------------------------------------------
__global__ __launch_bounds__(256) void k_xx(const float* __restrict__ x,
                                            double* __restrict__ xx) {
  int i = blockIdx.x * 256 + threadIdx.x;          // 0..16383
  int b = i >> 11, j = i & (NN - 1);
  const float* p = x + ((size_t)b * CC) * NN + j;
  double s = 0.0;
#pragma unroll
  for (int c = 0; c < CC; ++c) { double v = (double)p[(size_t)c * NN]; s = fma(v, v, s); }
  xx[i] = s;
}

// ---------------------------------------------------------------------------
// K1: fused score GEMM (fp64) + top-20 selection.
// Block = 256 thr (4 waves) handles 4 rows i of one batch; scores for all
// 2048 j kept in LDS (4*2048 doubles = exactly 64KB). Each thread computes
// 4 rows x 8 contiguous j. Selection: wave w owns row w; lane owns 32
// scores in regs; 20x (local argmax -> wave argmax w/ smaller-j tie-break).
// ---------------------------------------------------------------------------
__global__ __launch_bounds__(256) void k_knn(const float* __restrict__ x,
                                             const double* __restrict__ xx,
                                             int* __restrict__ idx) {
  __shared__ double S[4][NN];                      // 65536 B
  const int t = threadIdx.x;
  const int b = blockIdx.x >> 9;                   // 512 blocks per batch
  const int i0 = (blockIdx.x & 511) << 2;

  double acc[4][8];
#pragma unroll
  for (int r = 0; r < 4; ++r)
#pragma unroll
    for (int jj = 0; jj < 8; ++jj) acc[r][jj] = 0.0;

  const int j0 = t << 3;                           // 8 contiguous j per thread
  const float* xb = x + ((size_t)b * CC) * NN + j0;
  const float* xibase = x + ((size_t)b * CC) * NN + i0;   // uniform loads

#pragma unroll 2
  for (int cq = 0; cq < CC / 4; ++cq) {
#pragma unroll
    for (int c4 = 0; c4 < 4; ++c4) {
      const int c = cq * 4 + c4;
      float4 a0 = *(const float4*)(xb + (size_t)c * NN);
      float4 a1 = *(const float4*)(xb + (size_t)c * NN + 4);
      double xd[8] = {(double)a0.x, (double)a0.y, (double)a0.z, (double)a0.w,
                      (double)a1.x, (double)a1.y, (double)a1.z, (double)a1.w};
#pragma unroll
      for (int r = 0; r < 4; ++r) {
        double xiv = (double)xibase[(size_t)c * NN + r];   // wave-uniform
#pragma unroll
        for (int jj = 0; jj < 8; ++jj) acc[r][jj] = fma(xiv, xd[jj], acc[r][jj]);
      }
    }
  }

  {
    const double* xxb = xx + (b << 11) + j0;
    double xv[8];
#pragma unroll
    for (int jj = 0; jj < 8; ++jj) xv[jj] = xxb[jj];
#pragma unroll
    for (int r = 0; r < 4; ++r)
#pragma unroll
      for (int jj = 0; jj < 8; ++jj)
        S[r][j0 + jj] = 2.0 * acc[r][jj] - xv[jj];  // ordering == pd ordering
  }
  __syncthreads();

  const int wave = t >> 6, lane = t & 63;
  double v[32];
#pragma unroll
  for (int g = 0; g < 32; ++g) v[g] = S[wave][lane + (g << 6)];

  int* rowp = idx + (size_t)((b << 11) + i0 + wave) * KK;
  for (int kk = 0; kk < KK; ++kk) {
    double bv = v[0]; int bj = lane;               // j = lane + 64*g
#pragma unroll
    for (int g = 1; g < 32; ++g) {
      int j = lane + (g << 6);
      if (v[g] > bv) { bv = v[g]; bj = j; }        // first-wins => smaller j on tie
    }
#pragma unroll
    for (int off = 32; off > 0; off >>= 1) {
      double ov = __shfl_xor(bv, off, 64);
      int    oj = __shfl_xor(bj, off, 64);
      if (ov > bv || (ov == bv && oj < bj)) { bv = ov; bj = oj; }
    }
    if (lane == 0) rowp[kk] = bj;
    bool mine = (bj & 63) == lane;
    int gs = bj >> 6;
#pragma unroll
    for (int g = 0; g < 32; ++g) v[g] = (mine && g == gs) ? -1.0e300 : v[g];
  }
}

// ---------------------------------------------------------------------------
// K2: P[b][j][o] = sum_c x[b][c][j] * W[o][c]
//     Q[b][i][o] = sum_c x[b][c][i] * (W[o][64+c] - W[o][c])
// Block = 256 thr = 64 points x 4 o-groups(32). Two passes through one
// padded LDS tile (<=64KB static) for coalesced [pt][o] writes.
// ---------------------------------------------------------------------------
__global__ __launch_bounds__(256) void k_pq(const float* __restrict__ x,
                                            const float* __restrict__ W,
                                            float* __restrict__ P,
                                            float* __restrict__ Q) {
  __shared__ float tile[64][OO + 1];               // 33KB
  const int t = threadIdx.x;
  const int jj = t & 63, og = t >> 6;
  const int pt0 = blockIdx.x * 64;
  const int b = pt0 >> 11;
  const int jn = (pt0 & (NN - 1)) + jj;

  float xcol[CC];
#pragma unroll
  for (int c = 0; c < CC; ++c) xcol[c] = x[((size_t)(b * CC + c) << 11) + jn];

  // pass 1: P
  for (int oo = 0; oo < 32; ++oo) {
    int o = og * 32 + oo;
    const float* wr = W + (size_t)o * (2 * CC);
    float sp = 0.f;
#pragma unroll
    for (int c = 0; c < CC; ++c) sp = fmaf(wr[c], xcol[c], sp);
    tile[jj][o] = sp;
  }
  __syncthreads();
  for (int it = 0; it < 32; ++it) {
    int r = it * 2 + (t >> 7);
    P[((size_t)(pt0 + r)) * OO + (t & 127)] = tile[r][t & 127];
  }
  __syncthreads();
  // pass 2: Q
  for (int oo = 0; oo < 32; ++oo) {
    int o = og * 32 + oo;
    const float* wr = W + (size_t)o * (2 * CC);
    float sq = 0.f;
#pragma unroll
    for (int c = 0; c < CC; ++c) sq = fmaf(wr[CC + c] - wr[c], xcol[c], sq);
    tile[jj][o] = sq;
  }
  __syncthreads();
  for (int it = 0; it < 32; ++it) {
    int r = it * 2 + (t >> 7);
    Q[((size_t)(pt0 + r)) * OO + (t & 127)] = tile[r][t & 127];
  }
}

// ---------------------------------------------------------------------------
// K3: per-o sum & sumsq of h = P[gather] + Q, deterministic block partials.
// 512 blocks x 32 points. bid swizzle: one batch per XCD for L2 locality.
// ---------------------------------------------------------------------------
__global__ __launch_bounds__(256) void k_stats(const float* __restrict__ P,
                                               const float* __restrict__ Q,
                                               const int* __restrict__ idx,
                                               float* __restrict__ partial) {
  const int t = threadIdx.x;
  const int o = t & 127, half = t >> 7;
  const int bid = (blockIdx.x & 7) * 64 + (blockIdx.x >> 3);
  float s = 0.f, s2 = 0.f;
  for (int it = 0; it < 16; ++it) {
    int pt = bid * 32 + it * 2 + half;
    int b = pt >> 11;
    float qv = Q[(size_t)pt * OO + o];
    const int* ip = idx + (size_t)pt * KK;
#pragma unroll
    for (int k = 0; k < KK; ++k) {
      float v = P[((size_t)((b << 11) + ip[k])) * OO + o] + qv;
      s += v;
      s2 = fmaf(v, v, s2);
    }
  }
  __shared__ float red[512];
  red[t] = s; red[256 + t] = s2;
  __syncthreads();
  if (t < 128) {
    partial[bid * 128 + o]             = red[t] + red[t + 128];
    partial[512 * 128 + bid * 128 + o] = red[256 + t] + red[256 + t + 128];
  }
}

// ---------------------------------------------------------------------------
// K4: finalize BN -> scale/shift per o.
// ---------------------------------------------------------------------------
__global__ __launch_bounds__(256) void k_fin(const float* __restrict__ partial,
                                             const float* __restrict__ gamma,
                                             const float* __restrict__ beta,
                                             float* __restrict__ ss) {
  __shared__ float red[512];
  int t = threadIdx.x;
  int o = t & 127, h = t >> 7;
  float s = 0.f, s2 = 0.f;
  for (int blk = h; blk < 512; blk += 2) {
    s  += partial[blk * 128 + o];
    s2 += partial[512 * 128 + blk * 128 + o];
  }
  red[t] = s; red[256 + t] = s2;
  __syncthreads();
  if (t < 128) {
    float st  = red[t] + red[t + 128];
    float s2t = red[256 + t] + red[256 + t + 128];
    float mean = st * (1.0f / M_TOT);
    float var  = s2t * (1.0f / M_TOT) - mean * mean;
    float rs = 1.0f / sqrtf(var + 1e-5f);
    float scale = gamma[t] * rs;
    ss[t] = scale;
    ss[128 + t] = beta[t] - mean * scale;
  }
}

// ---------------------------------------------------------------------------
// K5: h = P[gather]+Q -> BN affine -> exact GELU -> max over k -> out[b][o][n].
// gelu is quasiconvex-decreasing/increasing with min at -0.7518, so
// max_k gelu(y_k) = gelu(ymax) if ymax>0 else max(gelu(ymax), gelu(ymin)).
// LDS transpose for coalesced (B,O,N) stores.
// ---------------------------------------------------------------------------
__global__ __launch_bounds__(256) void k_out(const float* __restrict__ P,
                                             const float* __restrict__ Q,
                                             const int* __restrict__ idx,
                                             const float* __restrict__ ss,
                                             float* __restrict__ out) {
  __shared__ float tile[64][OO + 1];               // 33KB
  const int t = threadIdx.x;
  const int o = t & 127, half = t >> 7;
  const int bid = (blockIdx.x & 7) * 32 + (blockIdx.x >> 3);
  const float scale = ss[o], shift = ss[128 + o];
  const int pt0 = bid * 64;
  const int b = pt0 >> 11;
  const float inv_sqrt2 = 0.70710678118654752f;
  for (int it = 0; it < 32; ++it) {
    int pl = it * 2 + half;
    int pt = pt0 + pl;
    float qv = Q[(size_t)pt * OO + o];
    const int* ip = idx + (size_t)pt * KK;
    float vmax = -3.0e38f, vmin = 3.0e38f;
#pragma unroll
    for (int k = 0; k < KK; ++k) {
      float v = P[((size_t)((b << 11) + ip[k])) * OO + o] + qv;
      vmax = fmaxf(vmax, v);
      vmin = fminf(vmin, v);
    }
    float ymax, ymin;
    if (scale >= 0.f) { ymax = fmaf(vmax, scale, shift); ymin = fmaf(vmin, scale, shift); }
    else              { ymax = fmaf(vmin, scale, shift); ymin = fmaf(vmax, scale, shift); }
    float g;
    if (ymax > 0.f) {
      g = 0.5f * ymax * (1.0f + erff(ymax * inv_sqrt2));
    } else {
      float g1 = 0.5f * ymax * (1.0f + erff(ymax * inv_sqrt2));
      float g2 = 0.5f * ymin * (1.0f + erff(ymin * inv_sqrt2));
      g = fmaxf(g1, g2);
    }
    tile[pl][o] = g;
  }
  __syncthreads();
  const int n0 = pt0 & (NN - 1);
  for (int rep = 0; rep < 32; ++rep) {
    int oo = rep * 4 + (t >> 6);
    int nn = t & 63;
    out[((size_t)(b * OO + oo) << 11) + n0 + nn] = tile[nn][oo];
  }
}

// ---------------------------------------------------------------------------
extern "C" void kernel_launch(void* const* d_in, const int* in_sizes, int n_in,
                              void* d_out, int out_size, void* d_ws, size_t ws_size,
                              hipStream_t stream) {
  const float* x     = (const float*)d_in[0];
  const float* W     = (const float*)d_in[1];
  const float* gamma = (const float*)d_in[2];
  const float* beta  = (const float*)d_in[3];
  float* out = (float*)d_out;

  // ws layout (~18 MB): xx(f64) | idx(i32) | P | Q | partial | ss
  double* xx   = (double*)d_ws;                        // 16384 * 8B
  int*    idx  = (int*)(xx + BB * NN);                 // 327680 * 4B
  float*  P    = (float*)(idx + BB * NN * KK);         // 2097152 * 4B
  float*  Q    = P + (size_t)BB * NN * OO;             // 2097152 * 4B
  float*  part = Q + (size_t)BB * NN * OO;             // 2*512*128 * 4B
  float*  ss   = part + 2 * 512 * 128;                 // 256 * 4B

  hipLaunchKernelGGL(k_xx,    dim3(BB * NN / 256), dim3(256), 0, stream, x, xx);
  hipLaunchKernelGGL(k_knn,   dim3(BB * NN / 4),   dim3(256), 0, stream, x, xx, idx);
  hipLaunchKernelGGL(k_pq,    dim3(BB * NN / 64),  dim3(256), 0, stream, x, W, P, Q);
  hipLaunchKernelGGL(k_stats, dim3(512),           dim3(256), 0, stream, P, Q, idx, part);
  hipLaunchKernelGGL(k_fin,   dim3(1),             dim3(256), 0, stream, part, gamma, beta, ss);
  hipLaunchKernelGGL(k_out,   dim3(BB * NN / 64),  dim3(256), 0, stream, P, Q, idx, ss, out);
}

// Round 2
// 331.726 us; speedup vs baseline: 1.5690x; 1.5690x over previous
//
#include <hip/hip_runtime.h>
#include <math.h>

#define BB 8
#define CC 64
#define NN 2048
#define KK 20
#define OO 128
#define CAND 24
#define M_TOT 327680.0f   // B*N*K

// ---------------------------------------------------------------------------
// K0: xx[b][j] = sum_c x[b][c][j]^2 in fp64 (exact: fp32*fp32 is exact in f64)
// ---------------------------------------------------------------------------
__global__ __launch_bounds__(256) void k_xx(const float* __restrict__ x,
                                            double* __restrict__ xx) {
  int i = blockIdx.x * 256 + threadIdx.x;          // 0..16383
  int b = i >> 11, j = i & (NN - 1);
  const float* p = x + ((size_t)b * CC) * NN + j;
  double s = 0.0;
#pragma unroll
  for (int c = 0; c < CC; ++c) { double v = (double)p[(size_t)c * NN]; s = fma(v, v, s); }
  xx[i] = s;
}

// ---------------------------------------------------------------------------
// K1: fused fp32 score GEMM + top-24 candidate selection + fp64 rescore.
// Block = 512 thr (8 waves) handles 8 rows of one batch; fp32 scores for all
// 2048 j in 64KB LDS. Selection: wave w owns row w; each lane keeps a sorted
// top-4 of its 32 scores (exact refill when exhausted); 24 rounds of wave
// argmax (f32) -> candidates; candidates rescored in fp64 (exact) and ranked
// by (score desc, j asc) == lax.top_k stable order. fp32 dot error (~2e-4)
// << rank-20..24 score gap => exact top-20 always within the 24 candidates.
// ---------------------------------------------------------------------------
#define NEGF (-3.0e38f)
#define INS(v, j) do {                                              \
    bool c0 = (v) > s0, c1 = (v) > s1, c2 = (v) > s2, c3 = (v) > s3; \
    s3 = c2 ? s2 : (c3 ? (v) : s3); q3 = c2 ? q2 : (c3 ? (j) : q3);  \
    s2 = c1 ? s1 : (c2 ? (v) : s2); q2 = c1 ? q1 : (c2 ? (j) : q2);  \
    s1 = c0 ? s0 : (c1 ? (v) : s1); q1 = c0 ? q0 : (c1 ? (j) : q1);  \
    s0 = c0 ? (v) : s0;             q0 = c0 ? (j) : q0;              \
  } while (0)

__global__ __launch_bounds__(512, 4) void k_knn(const float* __restrict__ x,
                                                const double* __restrict__ xx,
                                                int* __restrict__ idx) {
  __shared__ float S[8][NN];                       // 65536 B
  const int t = threadIdx.x;
  const int b = blockIdx.x >> 8;                   // 256 blocks per batch
  const int i0 = (blockIdx.x & 255) << 3;          // 8 rows per block
  const float* xb = x + ((size_t)b * CC) * NN;

  // ---- compute phase: fp32 scores, 8 rows x 4 j per thread ----
  {
    const int j0 = t << 2;
    float acc[8][4];
#pragma unroll
    for (int r = 0; r < 8; ++r)
#pragma unroll
      for (int jj = 0; jj < 4; ++jj) acc[r][jj] = 0.f;

#pragma unroll 4
    for (int c = 0; c < CC; ++c) {
      float4 a = *(const float4*)(xb + (size_t)c * NN + j0);
#pragma unroll
      for (int r = 0; r < 8; ++r) {
        float xiv = xb[(size_t)c * NN + i0 + r];   // uniform -> scalar load
        acc[r][0] = fmaf(xiv, a.x, acc[r][0]);
        acc[r][1] = fmaf(xiv, a.y, acc[r][1]);
        acc[r][2] = fmaf(xiv, a.z, acc[r][2]);
        acc[r][3] = fmaf(xiv, a.w, acc[r][3]);
      }
    }
    float xv[4];
#pragma unroll
    for (int jj = 0; jj < 4; ++jj) xv[jj] = (float)xx[(b << 11) + j0 + jj];
#pragma unroll
    for (int r = 0; r < 8; ++r)
#pragma unroll
      for (int jj = 0; jj < 4; ++jj)
        S[r][j0 + jj] = fmaf(2.f, acc[r][jj], -xv[jj]);
  }
  __syncthreads();

  // ---- selection phase: wave w owns row i0+w ----
  const int w = t >> 6, lane = t & 63;
  float s0 = NEGF, s1 = NEGF, s2 = NEGF, s3 = NEGF;
  int q0 = 1 << 30, q1 = 1 << 30, q2 = 1 << 30, q3 = 1 << 30;
  unsigned taken = 0u;
#pragma unroll
  for (int g = 0; g < 32; ++g) {
    float v = S[w][lane + (g << 6)];
    int j = lane + (g << 6);
    INS(v, j);
  }
  int cnt = 4;
  int cj = 0;                                      // candidate held at lane kk

  for (int kk = 0; kk < CAND; ++kk) {
    float bv = (cnt > 0) ? s0 : NEGF;
    int bj = (cnt > 0) ? q0 : (1 << 30);
#pragma unroll
    for (int off = 32; off > 0; off >>= 1) {
      float ov = __shfl_xor(bv, off, 64);
      int oj = __shfl_xor(bj, off, 64);
      if (ov > bv || (ov == bv && oj < bj)) { bv = ov; bj = oj; }
    }
    if (kk == lane) cj = bj;
    if ((bj & 63) == lane) {                       // this lane owned the winner
      taken |= 1u << (bj >> 6);
      s0 = s1; q0 = q1; s1 = s2; q1 = q2; s2 = s3; q2 = q3;
      s3 = NEGF; q3 = 1 << 30;
      if (--cnt == 0) {                            // exact refill (rare)
        s0 = s1 = s2 = s3 = NEGF;
        q0 = q1 = q2 = q3 = 1 << 30;
        for (int g = 0; g < 32; ++g) {
          if (!((taken >> g) & 1u)) {
            float v = S[w][lane + (g << 6)];
            int j = lane + (g << 6);
            INS(v, j);
          }
        }
        cnt = 4;                                   // >=4 always remain (32-24>4)
      }
    }
  }

  // ---- fp64 rescore of the 24 candidates (exact ordering) ----
  int j = (lane < CAND) ? cj : 0;
  double inner = 0.0;
#pragma unroll 4
  for (int c = 0; c < CC; ++c) {
    double xiv = (double)xb[(size_t)c * NN + i0 + w];   // uniform
    double xjv = (double)xb[(size_t)c * NN + j];        // gather
    inner = fma(xiv, xjv, inner);
  }
  double sc = 2.0 * inner - xx[(b << 11) + j];
  int rank = 0;
#pragma unroll
  for (int m = 0; m < CAND; ++m) {
    double sm = __shfl(sc, m, 64);
    int jm = __shfl(j, m, 64);
    rank += (sm > sc || (sm == sc && jm < j)) ? 1 : 0;
  }
  if (lane < CAND && rank < KK)
    idx[(size_t)((b << 11) + i0 + w) * KK + rank] = j;
}

// ---------------------------------------------------------------------------
// K2: P[b][j][o] = sum_c x[b][c][j] * W[o][c]
//     Q[b][i][o] = sum_c x[b][c][i] * (W[o][64+c] - W[o][c])
// ---------------------------------------------------------------------------
__global__ __launch_bounds__(256) void k_pq(const float* __restrict__ x,
                                            const float* __restrict__ W,
                                            float* __restrict__ P,
                                            float* __restrict__ Q) {
  __shared__ float tile[64][OO + 1];               // 33KB
  const int t = threadIdx.x;
  const int jj = t & 63, og = t >> 6;
  const int pt0 = blockIdx.x * 64;
  const int b = pt0 >> 11;
  const int jn = (pt0 & (NN - 1)) + jj;

  float xcol[CC];
#pragma unroll
  for (int c = 0; c < CC; ++c) xcol[c] = x[((size_t)(b * CC + c) << 11) + jn];

  for (int oo = 0; oo < 32; ++oo) {
    int o = og * 32 + oo;
    const float* wr = W + (size_t)o * (2 * CC);
    float sp = 0.f;
#pragma unroll
    for (int c = 0; c < CC; ++c) sp = fmaf(wr[c], xcol[c], sp);
    tile[jj][o] = sp;
  }
  __syncthreads();
  for (int it = 0; it < 32; ++it) {
    int r = it * 2 + (t >> 7);
    P[((size_t)(pt0 + r)) * OO + (t & 127)] = tile[r][t & 127];
  }
  __syncthreads();
  for (int oo = 0; oo < 32; ++oo) {
    int o = og * 32 + oo;
    const float* wr = W + (size_t)o * (2 * CC);
    float sq = 0.f;
#pragma unroll
    for (int c = 0; c < CC; ++c) sq = fmaf(wr[CC + c] - wr[c], xcol[c], sq);
    tile[jj][o] = sq;
  }
  __syncthreads();
  for (int it = 0; it < 32; ++it) {
    int r = it * 2 + (t >> 7);
    Q[((size_t)(pt0 + r)) * OO + (t & 127)] = tile[r][t & 127];
  }
}

// ---------------------------------------------------------------------------
// K3: per-o sum & sumsq of h = P[gather] + Q, deterministic block partials.
// ---------------------------------------------------------------------------
__global__ __launch_bounds__(256) void k_stats(const float* __restrict__ P,
                                               const float* __restrict__ Q,
                                               const int* __restrict__ idx,
                                               float* __restrict__ partial) {
  const int t = threadIdx.x;
  const int o = t & 127, half = t >> 7;
  const int bid = (blockIdx.x & 7) * 64 + (blockIdx.x >> 3);
  float s = 0.f, s2 = 0.f;
  for (int it = 0; it < 16; ++it) {
    int pt = bid * 32 + it * 2 + half;
    int b = pt >> 11;
    float qv = Q[(size_t)pt * OO + o];
    const int* ip = idx + (size_t)pt * KK;
#pragma unroll
    for (int k = 0; k < KK; ++k) {
      float v = P[((size_t)((b << 11) + ip[k])) * OO + o] + qv;
      s += v;
      s2 = fmaf(v, v, s2);
    }
  }
  __shared__ float red[512];
  red[t] = s; red[256 + t] = s2;
  __syncthreads();
  if (t < 128) {
    partial[bid * 128 + o]             = red[t] + red[t + 128];
    partial[512 * 128 + bid * 128 + o] = red[256 + t] + red[256 + t + 128];
  }
}

// ---------------------------------------------------------------------------
// K4: finalize BN -> scale/shift per o.
// ---------------------------------------------------------------------------
__global__ __launch_bounds__(256) void k_fin(const float* __restrict__ partial,
                                             const float* __restrict__ gamma,
                                             const float* __restrict__ beta,
                                             float* __restrict__ ss) {
  __shared__ float red[512];
  int t = threadIdx.x;
  int o = t & 127, h = t >> 7;
  float s = 0.f, s2 = 0.f;
  for (int blk = h; blk < 512; blk += 2) {
    s  += partial[blk * 128 + o];
    s2 += partial[512 * 128 + blk * 128 + o];
  }
  red[t] = s; red[256 + t] = s2;
  __syncthreads();
  if (t < 128) {
    float st  = red[t] + red[t + 128];
    float s2t = red[256 + t] + red[256 + t + 128];
    float mean = st * (1.0f / M_TOT);
    float var  = s2t * (1.0f / M_TOT) - mean * mean;
    float rs = 1.0f / sqrtf(var + 1e-5f);
    float scale = gamma[t] * rs;
    ss[t] = scale;
    ss[128 + t] = beta[t] - mean * scale;
  }
}

// ---------------------------------------------------------------------------
// K5: h = P[gather]+Q -> BN affine -> exact GELU -> max over k -> out[b][o][n].
// max_k gelu(y_k) = gelu(ymax) if ymax>0 else max(gelu(ymax), gelu(ymin)).
// ---------------------------------------------------------------------------
__global__ __launch_bounds__(256) void k_out(const float* __restrict__ P,
                                             const float* __restrict__ Q,
                                             const int* __restrict__ idx,
                                             const float* __restrict__ ss,
                                             float* __restrict__ out) {
  __shared__ float tile[64][OO + 1];               // 33KB
  const int t = threadIdx.x;
  const int o = t & 127, half = t >> 7;
  const int bid = (blockIdx.x & 7) * 32 + (blockIdx.x >> 3);
  const float scale = ss[o], shift = ss[128 + o];
  const int pt0 = bid * 64;
  const int b = pt0 >> 11;
  const float inv_sqrt2 = 0.70710678118654752f;
  for (int it = 0; it < 32; ++it) {
    int pl = it * 2 + half;
    int pt = pt0 + pl;
    float qv = Q[(size_t)pt * OO + o];
    const int* ip = idx + (size_t)pt * KK;
    float vmax = -3.0e38f, vmin = 3.0e38f;
#pragma unroll
    for (int k = 0; k < KK; ++k) {
      float v = P[((size_t)((b << 11) + ip[k])) * OO + o] + qv;
      vmax = fmaxf(vmax, v);
      vmin = fminf(vmin, v);
    }
    float ymax, ymin;
    if (scale >= 0.f) { ymax = fmaf(vmax, scale, shift); ymin = fmaf(vmin, scale, shift); }
    else              { ymax = fmaf(vmin, scale, shift); ymin = fmaf(vmax, scale, shift); }
    float g;
    if (ymax > 0.f) {
      g = 0.5f * ymax * (1.0f + erff(ymax * inv_sqrt2));
    } else {
      float g1 = 0.5f * ymax * (1.0f + erff(ymax * inv_sqrt2));
      float g2 = 0.5f * ymin * (1.0f + erff(ymin * inv_sqrt2));
      g = fmaxf(g1, g2);
    }
    tile[pl][o] = g;
  }
  __syncthreads();
  const int n0 = pt0 & (NN - 1);
  for (int rep = 0; rep < 32; ++rep) {
    int oo = rep * 4 + (t >> 6);
    int nn = t & 63;
    out[((size_t)(b * OO + oo) << 11) + n0 + nn] = tile[nn][oo];
  }
}

// ---------------------------------------------------------------------------
extern "C" void kernel_launch(void* const* d_in, const int* in_sizes, int n_in,
                              void* d_out, int out_size, void* d_ws, size_t ws_size,
                              hipStream_t stream) {
  const float* x     = (const float*)d_in[0];
  const float* W     = (const float*)d_in[1];
  const float* gamma = (const float*)d_in[2];
  const float* beta  = (const float*)d_in[3];
  float* out = (float*)d_out;

  double* xx   = (double*)d_ws;                        // 16384 * 8B
  int*    idx  = (int*)(xx + BB * NN);                 // 327680 * 4B
  float*  P    = (float*)(idx + BB * NN * KK);         // 2097152 * 4B
  float*  Q    = P + (size_t)BB * NN * OO;             // 2097152 * 4B
  float*  part = Q + (size_t)BB * NN * OO;             // 2*512*128 * 4B
  float*  ss   = part + 2 * 512 * 128;                 // 256 * 4B

  hipLaunchKernelGGL(k_xx,    dim3(BB * NN / 256), dim3(256), 0, stream, x, xx);
  hipLaunchKernelGGL(k_knn,   dim3(BB * NN / 8),   dim3(512), 0, stream, x, xx, idx);
  hipLaunchKernelGGL(k_pq,    dim3(BB * NN / 64),  dim3(256), 0, stream, x, W, P, Q);
  hipLaunchKernelGGL(k_stats, dim3(512),           dim3(256), 0, stream, P, Q, idx, part);
  hipLaunchKernelGGL(k_fin,   dim3(1),             dim3(256), 0, stream, part, gamma, beta, ss);
  hipLaunchKernelGGL(k_out,   dim3(BB * NN / 64),  dim3(256), 0, stream, P, Q, idx, ss, out);
}

// Round 3
// 308.804 us; speedup vs baseline: 1.6854x; 1.0742x over previous
//
#include <hip/hip_runtime.h>
#include <math.h>

#define BB 8
#define CC 64
#define NN 2048
#define KK 20
#define OO 128
#define CANDT 40
#define M_TOT 327680.0f   // B*N*K

typedef __attribute__((ext_vector_type(8))) __bf16 bf8v;
typedef __attribute__((ext_vector_type(16))) float f32x16;

// ---------------------------------------------------------------------------
// K0: prep — xT[b][n][c] bf16 (for MFMA frags), xx fp64, xxf f32.
// ---------------------------------------------------------------------------
__global__ __launch_bounds__(256) void k_prep(const float* __restrict__ x,
                                              ushort* __restrict__ xT,
                                              double* __restrict__ xx,
                                              float* __restrict__ xxf) {
  int i = blockIdx.x * 256 + threadIdx.x;          // b*2048 + n
  int b = i >> 11, n = i & (NN - 1);
  const float* p = x + ((size_t)b * CC) * NN + n;
  ushort* rowp = xT + (size_t)i * CC;
  double s = 0.0;
#pragma unroll
  for (int c8 = 0; c8 < 8; ++c8) {
    unsigned tmp[8];
#pragma unroll
    for (int e = 0; e < 8; ++e) {
      float v = p[(size_t)(c8 * 8 + e) * NN];
      double dv = (double)v; s = fma(dv, dv, s);
      __bf16 h = (__bf16)v;
      ushort us; __builtin_memcpy(&us, &h, 2);
      tmp[e] = us;
    }
    uint4 pk;
    pk.x = tmp[0] | (tmp[1] << 16);
    pk.y = tmp[2] | (tmp[3] << 16);
    pk.z = tmp[4] | (tmp[5] << 16);
    pk.w = tmp[6] | (tmp[7] << 16);
    *(uint4*)(rowp + c8 * 8) = pk;
  }
  xx[i] = s;
  xxf[i] = (float)s;
}

// ---------------------------------------------------------------------------
// K1: KNN. Block=1024thr (16 waves), 32 rows x 2048 cols of one batch.
// Phase A: MFMA 32x32x16 bf16 — wave w covers cols [w*128, w*128+128).
//   A/B frags: identical per-lane pattern (row=l&31, k=8*(l>>5)+e) loaded as
//   contiguous 16B from xT — k-permutation errors cancel between A and B.
// Phase B: scores (2*acc - xxf[j]) -> bf16 in 128KB LDS; acc regs die.
// Phase C: per row (wave w: rows w, w+16): monotone 16-bit keys, per-lane
//   top-4, MSB radix w/ ballot counts -> tau ~ 40th largest; exact count +
//   prefix-scan compaction -> <=64 candidates; fp64 rescore (exact) ->
//   rank by (score desc, j asc) -> top-20. Selection-set margin: gap
//   rank20->rank40 ~ 8 >> bf16 score error ~0.3.
// ---------------------------------------------------------------------------
__global__ __launch_bounds__(1024, 4) void k_knn(
    const ushort* __restrict__ xT, const float* __restrict__ xxf,
    const float* __restrict__ x, const double* __restrict__ xx,
    int* __restrict__ idx) {
  extern __shared__ char smem[];
  ushort (*Sb)[NN] = (ushort(*)[NN])smem;          // [32][2048] = 128 KB
  int* Cj = (int*)(smem + 32 * NN * 2);            // [16][64]
  const int t = threadIdx.x;
  const int w = t >> 6, lane = t & 63;
  const int b = blockIdx.x >> 6;
  const int i0 = (blockIdx.x & 63) << 5;
  const int lr = lane & 31, lh = lane >> 5;
  const ushort* xTb = xT + ((((size_t)b) << 11)) * CC;

  f32x16 acc[4];
#pragma unroll
  for (int tt = 0; tt < 4; ++tt)
#pragma unroll
    for (int q = 0; q < 16; ++q) acc[tt][q] = 0.f;

  const ushort* Ap = xTb + (size_t)(i0 + lr) * CC + lh * 8;
  bf8v a0 = *(const bf8v*)(Ap);
  bf8v a1 = *(const bf8v*)(Ap + 16);
  bf8v a2 = *(const bf8v*)(Ap + 32);
  bf8v a3 = *(const bf8v*)(Ap + 48);
  const int j0w = w << 7;
#pragma unroll
  for (int tt = 0; tt < 4; ++tt) {
    const ushort* Bp = xTb + (size_t)(j0w + tt * 32 + lr) * CC + lh * 8;
    bf8v b0 = *(const bf8v*)(Bp);
    bf8v b1 = *(const bf8v*)(Bp + 16);
    bf8v b2 = *(const bf8v*)(Bp + 32);
    bf8v b3 = *(const bf8v*)(Bp + 48);
    acc[tt] = __builtin_amdgcn_mfma_f32_32x32x16_bf16(a0, b0, acc[tt], 0, 0, 0);
    acc[tt] = __builtin_amdgcn_mfma_f32_32x32x16_bf16(a1, b1, acc[tt], 0, 0, 0);
    acc[tt] = __builtin_amdgcn_mfma_f32_32x32x16_bf16(a2, b2, acc[tt], 0, 0, 0);
    acc[tt] = __builtin_amdgcn_mfma_f32_32x32x16_bf16(a3, b3, acc[tt], 0, 0, 0);
  }

  const float* xxfb = xxf + (b << 11);
#pragma unroll
  for (int tt = 0; tt < 4; ++tt) {
    int j = j0w + tt * 32 + lr;
    float xv = xxfb[j];
#pragma unroll
    for (int q = 0; q < 16; ++q) {
      int rr = (q & 3) + 8 * (q >> 2) + 4 * lh;    // C/D row mapping (m74/m101)
      float sv = 2.f * acc[tt][q] - xv;
      __bf16 hb = (__bf16)sv;
      ushort us; __builtin_memcpy(&us, &hb, 2);
      Sb[rr][j] = us;
    }
  }
  __syncthreads();

  const float* xb = x + ((size_t)b * CC) * NN;
  const double* xxb = xx + (b << 11);
#pragma unroll 1
  for (int rw = 0; rw < 2; ++rw) {
    const int rr = w + 16 * rw;
    const int irow = i0 + rr;
    // keys + per-lane top-4 (values only)
    unsigned u[32];
    unsigned t0 = 0, t1 = 0, t2 = 0, t3 = 0;
#pragma unroll
    for (int g = 0; g < 32; ++g) {
      unsigned raw = (unsigned)Sb[rr][lane + (g << 6)];
      unsigned key = raw ^ (0x8000u | ((raw >> 15) * 0x7FFFu)); // monotone
      u[g] = key;
      unsigned mx = key > t0 ? key : t0, mn = key > t0 ? t0 : key; t0 = mx;
      mx = mn > t1 ? mn : t1; mn = mn > t1 ? t1 : mn; t1 = mx;
      mx = mn > t2 ? mn : t2; mn = mn > t2 ? t2 : mn; t2 = mx;
      t3 = mn > t3 ? mn : t3;
    }
    // MSB-first radix on 16-bit keys, capped (top-4) ballot counts
    unsigned tau = 0;
    for (int bit = 15; bit >= 0; --bit) {
      unsigned cnd = tau | (1u << bit);
      unsigned long long B0 = __ballot(t0 >= cnd);
      unsigned long long B1 = __ballot(t1 >= cnd);
      unsigned long long B2 = __ballot(t2 >= cnd);
      unsigned long long B3 = __ballot(t3 >= cnd);
      int tot = __popcll(B0) + __popcll(B1) + __popcll(B2) + __popcll(B3);
      if (tot >= CANDT) tau = cnd;
    }
    // exact count + prefix scan
    int myc = 0;
#pragma unroll
    for (int g = 0; g < 32; ++g) myc += (u[g] >= tau) ? 1 : 0;
    int pre = myc;
#pragma unroll
    for (int off = 1; off < 64; off <<= 1) {
      int o = __shfl_up(pre, off, 64);
      pre += (lane >= off) ? o : 0;
    }
    int tot = __shfl(pre, 63, 64);
    if (tot > 64) {                                 // cold exact-radix fallback
      tau = 0;
      for (int bit = 15; bit >= 0; --bit) {
        unsigned cnd = tau | (1u << bit);
        int cc = 0;
#pragma unroll
        for (int g = 0; g < 32; ++g) cc += (u[g] >= cnd) ? 1 : 0;
#pragma unroll
        for (int off = 1; off < 64; off <<= 1) cc += __shfl_xor(cc, off, 64);
        if (cc >= CANDT) tau = cnd;
      }
      myc = 0;
#pragma unroll
      for (int g = 0; g < 32; ++g) myc += (u[g] >= tau) ? 1 : 0;
      pre = myc;
#pragma unroll
      for (int off = 1; off < 64; off <<= 1) {
        int o = __shfl_up(pre, off, 64);
        pre += (lane >= off) ? o : 0;
      }
      tot = __shfl(pre, 63, 64);
    }
    int base = pre - myc;
    int* cjw = Cj + w * 64;
    int slot = base;
#pragma unroll
    for (int g = 0; g < 32; ++g) {
      bool hit = (u[g] >= tau);
      if (hit && slot < 64) cjw[slot] = lane + (g << 6);
      slot += hit ? 1 : 0;
    }
    int cnt = tot > 64 ? 64 : tot;
    int j = cjw[lane < cnt ? lane : 0];
    // fp64 rescore (exact; 4 accumulators, deterministic)
    double d0 = 0, d1 = 0, d2 = 0, d3 = 0;
#pragma unroll 4
    for (int c = 0; c < CC; c += 4) {
      d0 = fma((double)xb[(size_t)c * NN + irow],       (double)xb[(size_t)c * NN + j], d0);
      d1 = fma((double)xb[(size_t)(c + 1) * NN + irow], (double)xb[(size_t)(c + 1) * NN + j], d1);
      d2 = fma((double)xb[(size_t)(c + 2) * NN + irow], (double)xb[(size_t)(c + 2) * NN + j], d2);
      d3 = fma((double)xb[(size_t)(c + 3) * NN + irow], (double)xb[(size_t)(c + 3) * NN + j], d3);
    }
    double sc = 2.0 * ((d0 + d1) + (d2 + d3)) - xxb[j];
    int rank = 0;
    for (int mm = 0; mm < cnt; ++mm) {
      double sm = __shfl(sc, mm, 64);
      int jm = __shfl(j, mm, 64);
      rank += (sm > sc || (sm == sc && jm < j)) ? 1 : 0;
    }
    if (lane < cnt && rank < KK)
      idx[(size_t)((b << 11) + irow) * KK + rank] = j;
  }
}

// ---------------------------------------------------------------------------
// K2: P[b][j][o] = sum_c x[b][c][j] * W[o][c]
//     Q[b][i][o] = sum_c x[b][c][i] * (W[o][64+c] - W[o][c])
// ---------------------------------------------------------------------------
__global__ __launch_bounds__(256) void k_pq(const float* __restrict__ x,
                                            const float* __restrict__ W,
                                            float* __restrict__ P,
                                            float* __restrict__ Q) {
  __shared__ float tile[64][OO + 1];               // 33KB
  const int t = threadIdx.x;
  const int jj = t & 63, og = t >> 6;
  const int pt0 = blockIdx.x * 64;
  const int b = pt0 >> 11;
  const int jn = (pt0 & (NN - 1)) + jj;

  float xcol[CC];
#pragma unroll
  for (int c = 0; c < CC; ++c) xcol[c] = x[((size_t)(b * CC + c) << 11) + jn];

  for (int oo = 0; oo < 32; ++oo) {
    int o = og * 32 + oo;
    const float* wr = W + (size_t)o * (2 * CC);
    float sp = 0.f;
#pragma unroll
    for (int c = 0; c < CC; ++c) sp = fmaf(wr[c], xcol[c], sp);
    tile[jj][o] = sp;
  }
  __syncthreads();
  for (int it = 0; it < 32; ++it) {
    int r = it * 2 + (t >> 7);
    P[((size_t)(pt0 + r)) * OO + (t & 127)] = tile[r][t & 127];
  }
  __syncthreads();
  for (int oo = 0; oo < 32; ++oo) {
    int o = og * 32 + oo;
    const float* wr = W + (size_t)o * (2 * CC);
    float sq = 0.f;
#pragma unroll
    for (int c = 0; c < CC; ++c) sq = fmaf(wr[CC + c] - wr[c], xcol[c], sq);
    tile[jj][o] = sq;
  }
  __syncthreads();
  for (int it = 0; it < 32; ++it) {
    int r = it * 2 + (t >> 7);
    Q[((size_t)(pt0 + r)) * OO + (t & 127)] = tile[r][t & 127];
  }
}

// ---------------------------------------------------------------------------
// K3: per-o sum & sumsq of h = P[gather] + Q, deterministic block partials.
// ---------------------------------------------------------------------------
__global__ __launch_bounds__(256) void k_stats(const float* __restrict__ P,
                                               const float* __restrict__ Q,
                                               const int* __restrict__ idx,
                                               float* __restrict__ partial) {
  const int t = threadIdx.x;
  const int o = t & 127, half = t >> 7;
  const int bid = (blockIdx.x & 7) * 64 + (blockIdx.x >> 3);
  float s = 0.f, s2 = 0.f;
  for (int it = 0; it < 16; ++it) {
    int pt = bid * 32 + it * 2 + half;
    int b = pt >> 11;
    float qv = Q[(size_t)pt * OO + o];
    const int* ip = idx + (size_t)pt * KK;
#pragma unroll
    for (int k = 0; k < KK; ++k) {
      float v = P[((size_t)((b << 11) + ip[k])) * OO + o] + qv;
      s += v;
      s2 = fmaf(v, v, s2);
    }
  }
  __shared__ float red[512];
  red[t] = s; red[256 + t] = s2;
  __syncthreads();
  if (t < 128) {
    partial[bid * 128 + o]             = red[t] + red[t + 128];
    partial[512 * 128 + bid * 128 + o] = red[256 + t] + red[256 + t + 128];
  }
}

// ---------------------------------------------------------------------------
// K4: finalize BN -> scale/shift per o.
// ---------------------------------------------------------------------------
__global__ __launch_bounds__(256) void k_fin(const float* __restrict__ partial,
                                             const float* __restrict__ gamma,
                                             const float* __restrict__ beta,
                                             float* __restrict__ ss) {
  __shared__ float red[512];
  int t = threadIdx.x;
  int o = t & 127, h = t >> 7;
  float s = 0.f, s2 = 0.f;
  for (int blk = h; blk < 512; blk += 2) {
    s  += partial[blk * 128 + o];
    s2 += partial[512 * 128 + blk * 128 + o];
  }
  red[t] = s; red[256 + t] = s2;
  __syncthreads();
  if (t < 128) {
    float st  = red[t] + red[t + 128];
    float s2t = red[256 + t] + red[256 + t + 128];
    float mean = st * (1.0f / M_TOT);
    float var  = s2t * (1.0f / M_TOT) - mean * mean;
    float rs = 1.0f / sqrtf(var + 1e-5f);
    float scale = gamma[t] * rs;
    ss[t] = scale;
    ss[128 + t] = beta[t] - mean * scale;
  }
}

// ---------------------------------------------------------------------------
// K5: h = P[gather]+Q -> BN affine -> exact GELU -> max over k -> out[b][o][n].
// max_k gelu(y_k) = gelu(ymax) if ymax>0 else max(gelu(ymax), gelu(ymin)).
// ---------------------------------------------------------------------------
__global__ __launch_bounds__(256) void k_out(const float* __restrict__ P,
                                             const float* __restrict__ Q,
                                             const int* __restrict__ idx,
                                             const float* __restrict__ ss,
                                             float* __restrict__ out) {
  __shared__ float tile[64][OO + 1];               // 33KB
  const int t = threadIdx.x;
  const int o = t & 127, half = t >> 7;
  const int bid = (blockIdx.x & 7) * 32 + (blockIdx.x >> 3);
  const float scale = ss[o], shift = ss[128 + o];
  const int pt0 = bid * 64;
  const int b = pt0 >> 11;
  const float inv_sqrt2 = 0.70710678118654752f;
  for (int it = 0; it < 32; ++it) {
    int pl = it * 2 + half;
    int pt = pt0 + pl;
    float qv = Q[(size_t)pt * OO + o];
    const int* ip = idx + (size_t)pt * KK;
    float vmax = -3.0e38f, vmin = 3.0e38f;
#pragma unroll
    for (int k = 0; k < KK; ++k) {
      float v = P[((size_t)((b << 11) + ip[k])) * OO + o] + qv;
      vmax = fmaxf(vmax, v);
      vmin = fminf(vmin, v);
    }
    float ymax, ymin;
    if (scale >= 0.f) { ymax = fmaf(vmax, scale, shift); ymin = fmaf(vmin, scale, shift); }
    else              { ymax = fmaf(vmin, scale, shift); ymin = fmaf(vmax, scale, shift); }
    float g;
    if (ymax > 0.f) {
      g = 0.5f * ymax * (1.0f + erff(ymax * inv_sqrt2));
    } else {
      float g1 = 0.5f * ymax * (1.0f + erff(ymax * inv_sqrt2));
      float g2 = 0.5f * ymin * (1.0f + erff(ymin * inv_sqrt2));
      g = fmaxf(g1, g2);
    }
    tile[pl][o] = g;
  }
  __syncthreads();
  const int n0 = pt0 & (NN - 1);
  for (int rep = 0; rep < 32; ++rep) {
    int oo = rep * 4 + (t >> 6);
    int nn = t & 63;
    out[((size_t)(b * OO + oo) << 11) + n0 + nn] = tile[nn][oo];
  }
}

// ---------------------------------------------------------------------------
extern "C" void kernel_launch(void* const* d_in, const int* in_sizes, int n_in,
                              void* d_out, int out_size, void* d_ws, size_t ws_size,
                              hipStream_t stream) {
  const float* x     = (const float*)d_in[0];
  const float* W     = (const float*)d_in[1];
  const float* gamma = (const float*)d_in[2];
  const float* beta  = (const float*)d_in[3];
  float* out = (float*)d_out;

  double* xx   = (double*)d_ws;                        // 131072 B
  int*    idxp = (int*)(xx + BB * NN);                 // 1310720 B
  float*  P    = (float*)(idxp + (size_t)BB * NN * KK);// 8 MB
  float*  Q    = P + (size_t)BB * NN * OO;             // 8 MB
  float*  part = Q + (size_t)BB * NN * OO;
  float*  ss   = part + 2 * 512 * 128;
  ushort* xT   = (ushort*)P;   // 2 MB alias — consumed by k_knn before k_pq writes P
  float*  xxf  = Q;            // 64 KB alias — consumed by k_knn before k_pq writes Q

  const int knn_lds = 32 * NN * 2 + 16 * 64 * 4;       // 135168 B
  hipFuncSetAttribute((const void*)k_knn,
                      hipFuncAttributeMaxDynamicSharedMemorySize, knn_lds);

  hipLaunchKernelGGL(k_prep,  dim3(BB * NN / 256), dim3(256),  0, stream, x, xT, xx, xxf);
  hipLaunchKernelGGL(k_knn,   dim3(BB * NN / 32),  dim3(1024), knn_lds, stream, xT, xxf, x, xx, idxp);
  hipLaunchKernelGGL(k_pq,    dim3(BB * NN / 64),  dim3(256),  0, stream, x, W, P, Q);
  hipLaunchKernelGGL(k_stats, dim3(512),           dim3(256),  0, stream, P, Q, idxp, part);
  hipLaunchKernelGGL(k_fin,   dim3(1),             dim3(256),  0, stream, part, gamma, beta, ss);
  hipLaunchKernelGGL(k_out,   dim3(BB * NN / 64),  dim3(256),  0, stream, P, Q, idxp, ss, out);
}

// Round 4
// 253.375 us; speedup vs baseline: 2.0542x; 1.2188x over previous
//
#include <hip/hip_runtime.h>
#include <math.h>

#define BB 8
#define CC 64
#define NN 2048
#define KK 20
#define OO 128
#define CANDT 40
#define M_TOT 327680.0f   // B*N*K

typedef __attribute__((ext_vector_type(8))) __bf16 bf8v;
typedef __attribute__((ext_vector_type(16))) float f32x16;

// ---------------------------------------------------------------------------
// K0: prep — xT[b][n][c] bf16 (MFMA frags), xTf[b][n][c] f32 (rescore rows),
//     xx fp64, xxf f32.
// ---------------------------------------------------------------------------
__global__ __launch_bounds__(256) void k_prep(const float* __restrict__ x,
                                              ushort* __restrict__ xT,
                                              float* __restrict__ xTf,
                                              double* __restrict__ xx,
                                              float* __restrict__ xxf) {
  int i = blockIdx.x * 256 + threadIdx.x;          // b*2048 + n
  int b = i >> 11, n = i & (NN - 1);
  const float* p = x + ((size_t)b * CC) * NN + n;
  ushort* rowp = xT + (size_t)i * CC;
  float* rowf = xTf + (size_t)i * CC;
  double s = 0.0;
#pragma unroll
  for (int c8 = 0; c8 < 8; ++c8) {
    float f[8];
    unsigned tmp[8];
#pragma unroll
    for (int e = 0; e < 8; ++e) {
      float v = p[(size_t)(c8 * 8 + e) * NN];
      f[e] = v;
      double dv = (double)v; s = fma(dv, dv, s);
      __bf16 h = (__bf16)v;
      ushort us; __builtin_memcpy(&us, &h, 2);
      tmp[e] = us;
    }
    uint4 pk;
    pk.x = tmp[0] | (tmp[1] << 16);
    pk.y = tmp[2] | (tmp[3] << 16);
    pk.z = tmp[4] | (tmp[5] << 16);
    pk.w = tmp[6] | (tmp[7] << 16);
    *(uint4*)(rowp + c8 * 8) = pk;
    *(float4*)(rowf + c8 * 8)     = make_float4(f[0], f[1], f[2], f[3]);
    *(float4*)(rowf + c8 * 8 + 4) = make_float4(f[4], f[5], f[6], f[7]);
  }
  xx[i] = s;
  xxf[i] = (float)s;
}

// ---------------------------------------------------------------------------
// K1: KNN. Block=1024thr (16 waves), 32 rows x 2048 cols of one batch.
// Phase A: MFMA 32x32x16 bf16 (A/B frag k-permutation cancels by symmetry).
// Phase B: scores (2*acc - xxf[j]) -> bf16 in 128KB LDS.
// Phase C: per row: monotone 16-bit keys, per-lane top-4, ballot radix ->
//   tau ~ 40th largest; compaction -> <=64 candidates; fp64 rescore from
//   contiguous xTf rows (exact, order-identical accumulation); rank by
//   (score desc, j asc) -> top-20.
// ---------------------------------------------------------------------------
__global__ __launch_bounds__(1024, 4) void k_knn(
    const ushort* __restrict__ xT, const float* __restrict__ xxf,
    const float* __restrict__ xTf, const double* __restrict__ xx,
    int* __restrict__ idx) {
  extern __shared__ char smem[];
  ushort (*Sb)[NN] = (ushort(*)[NN])smem;          // [32][2048] = 128 KB
  int* Cj = (int*)(smem + 32 * NN * 2);            // [16][64]
  const int t = threadIdx.x;
  const int w = t >> 6, lane = t & 63;
  const int b = blockIdx.x >> 6;
  const int i0 = (blockIdx.x & 63) << 5;
  const int lr = lane & 31, lh = lane >> 5;
  const ushort* xTb = xT + ((((size_t)b) << 11)) * CC;

  f32x16 acc[4];
#pragma unroll
  for (int tt = 0; tt < 4; ++tt)
#pragma unroll
    for (int q = 0; q < 16; ++q) acc[tt][q] = 0.f;

  const ushort* Ap = xTb + (size_t)(i0 + lr) * CC + lh * 8;
  bf8v a0 = *(const bf8v*)(Ap);
  bf8v a1 = *(const bf8v*)(Ap + 16);
  bf8v a2 = *(const bf8v*)(Ap + 32);
  bf8v a3 = *(const bf8v*)(Ap + 48);
  const int j0w = w << 7;
#pragma unroll
  for (int tt = 0; tt < 4; ++tt) {
    const ushort* Bp = xTb + (size_t)(j0w + tt * 32 + lr) * CC + lh * 8;
    bf8v b0 = *(const bf8v*)(Bp);
    bf8v b1 = *(const bf8v*)(Bp + 16);
    bf8v b2 = *(const bf8v*)(Bp + 32);
    bf8v b3 = *(const bf8v*)(Bp + 48);
    acc[tt] = __builtin_amdgcn_mfma_f32_32x32x16_bf16(a0, b0, acc[tt], 0, 0, 0);
    acc[tt] = __builtin_amdgcn_mfma_f32_32x32x16_bf16(a1, b1, acc[tt], 0, 0, 0);
    acc[tt] = __builtin_amdgcn_mfma_f32_32x32x16_bf16(a2, b2, acc[tt], 0, 0, 0);
    acc[tt] = __builtin_amdgcn_mfma_f32_32x32x16_bf16(a3, b3, acc[tt], 0, 0, 0);
  }

  const float* xxfb = xxf + (b << 11);
#pragma unroll
  for (int tt = 0; tt < 4; ++tt) {
    int j = j0w + tt * 32 + lr;
    float xv = xxfb[j];
#pragma unroll
    for (int q = 0; q < 16; ++q) {
      int rr = (q & 3) + 8 * (q >> 2) + 4 * lh;    // C/D row mapping (m74/m101)
      float sv = 2.f * acc[tt][q] - xv;
      __bf16 hb = (__bf16)sv;
      ushort us; __builtin_memcpy(&us, &hb, 2);
      Sb[rr][j] = us;
    }
  }
  __syncthreads();

  const float* xTfb = xTf + ((((size_t)b) << 11)) * CC;
  const double* xxb = xx + (b << 11);
#pragma unroll 1
  for (int rw = 0; rw < 2; ++rw) {
    const int rr = w + 16 * rw;
    const int irow = i0 + rr;
    // keys + per-lane top-4 (values only)
    unsigned u[32];
    unsigned t0 = 0, t1 = 0, t2 = 0, t3 = 0;
#pragma unroll
    for (int g = 0; g < 32; ++g) {
      unsigned raw = (unsigned)Sb[rr][lane + (g << 6)];
      unsigned key = raw ^ (0x8000u | ((raw >> 15) * 0x7FFFu)); // monotone
      u[g] = key;
      unsigned mx = key > t0 ? key : t0, mn = key > t0 ? t0 : key; t0 = mx;
      mx = mn > t1 ? mn : t1; mn = mn > t1 ? t1 : mn; t1 = mx;
      mx = mn > t2 ? mn : t2; mn = mn > t2 ? t2 : mn; t2 = mx;
      t3 = mn > t3 ? mn : t3;
    }
    // MSB-first radix on 16-bit keys, capped (top-4) ballot counts
    unsigned tau = 0;
    for (int bit = 15; bit >= 0; --bit) {
      unsigned cnd = tau | (1u << bit);
      unsigned long long B0 = __ballot(t0 >= cnd);
      unsigned long long B1 = __ballot(t1 >= cnd);
      unsigned long long B2 = __ballot(t2 >= cnd);
      unsigned long long B3 = __ballot(t3 >= cnd);
      int tot = __popcll(B0) + __popcll(B1) + __popcll(B2) + __popcll(B3);
      if (tot >= CANDT) tau = cnd;
    }
    // exact count + prefix scan
    int myc = 0;
#pragma unroll
    for (int g = 0; g < 32; ++g) myc += (u[g] >= tau) ? 1 : 0;
    int pre = myc;
#pragma unroll
    for (int off = 1; off < 64; off <<= 1) {
      int o = __shfl_up(pre, off, 64);
      pre += (lane >= off) ? o : 0;
    }
    int tot = __shfl(pre, 63, 64);
    if (tot > 64) {                                 // cold exact-radix fallback
      tau = 0;
      for (int bit = 15; bit >= 0; --bit) {
        unsigned cnd = tau | (1u << bit);
        int cc = 0;
#pragma unroll
        for (int g = 0; g < 32; ++g) cc += (u[g] >= cnd) ? 1 : 0;
#pragma unroll
        for (int off = 1; off < 64; off <<= 1) cc += __shfl_xor(cc, off, 64);
        if (cc >= CANDT) tau = cnd;
      }
      myc = 0;
#pragma unroll
      for (int g = 0; g < 32; ++g) myc += (u[g] >= tau) ? 1 : 0;
      pre = myc;
#pragma unroll
      for (int off = 1; off < 64; off <<= 1) {
        int o = __shfl_up(pre, off, 64);
        pre += (lane >= off) ? o : 0;
      }
      tot = __shfl(pre, 63, 64);
    }
    int base = pre - myc;
    int* cjw = Cj + w * 64;
    int slot = base;
#pragma unroll
    for (int g = 0; g < 32; ++g) {
      bool hit = (u[g] >= tau);
      if (hit && slot < 64) cjw[slot] = lane + (g << 6);
      slot += hit ? 1 : 0;
    }
    int cnt = tot > 64 ? 64 : tot;
    int j = cjw[lane < cnt ? lane : 0];
    // fp64 rescore from contiguous rows (exact; order-identical to R3)
    const float* xi = xTfb + (size_t)irow * CC;
    const float* xj = xTfb + (size_t)j * CC;
    double d0 = 0, d1 = 0, d2 = 0, d3 = 0;
#pragma unroll
    for (int c = 0; c < CC; c += 4) {
      float4 fi = *(const float4*)(xi + c);
      float4 fj = *(const float4*)(xj + c);
      d0 = fma((double)fi.x, (double)fj.x, d0);
      d1 = fma((double)fi.y, (double)fj.y, d1);
      d2 = fma((double)fi.z, (double)fj.z, d2);
      d3 = fma((double)fi.w, (double)fj.w, d3);
    }
    double sc = 2.0 * ((d0 + d1) + (d2 + d3)) - xxb[j];
    int rank = 0;
    for (int mm = 0; mm < cnt; ++mm) {
      double sm = __shfl(sc, mm, 64);
      int jm = __shfl(j, mm, 64);
      rank += (sm > sc || (sm == sc && jm < j)) ? 1 : 0;
    }
    if (lane < cnt && rank < KK)
      idx[(size_t)((b << 11) + irow) * KK + rank] = j;
  }
}

// ---------------------------------------------------------------------------
// K2: P[b][j][o] = sum_c x[b][c][j] * W[o][c]
//     Q[b][i][o] = sum_c x[b][c][i] * (W[o][64+c] - W[o][c])
// ---------------------------------------------------------------------------
__global__ __launch_bounds__(256) void k_pq(const float* __restrict__ x,
                                            const float* __restrict__ W,
                                            float* __restrict__ P,
                                            float* __restrict__ Q) {
  __shared__ float tile[64][OO + 1];               // 33KB
  const int t = threadIdx.x;
  const int jj = t & 63, og = t >> 6;
  const int pt0 = blockIdx.x * 64;
  const int b = pt0 >> 11;
  const int jn = (pt0 & (NN - 1)) + jj;

  float xcol[CC];
#pragma unroll
  for (int c = 0; c < CC; ++c) xcol[c] = x[((size_t)(b * CC + c) << 11) + jn];

  for (int oo = 0; oo < 32; ++oo) {
    int o = og * 32 + oo;
    const float* wr = W + (size_t)o * (2 * CC);
    float sp = 0.f;
#pragma unroll
    for (int c = 0; c < CC; ++c) sp = fmaf(wr[c], xcol[c], sp);
    tile[jj][o] = sp;
  }
  __syncthreads();
  for (int it = 0; it < 32; ++it) {
    int r = it * 2 + (t >> 7);
    P[((size_t)(pt0 + r)) * OO + (t & 127)] = tile[r][t & 127];
  }
  __syncthreads();
  for (int oo = 0; oo < 32; ++oo) {
    int o = og * 32 + oo;
    const float* wr = W + (size_t)o * (2 * CC);
    float sq = 0.f;
#pragma unroll
    for (int c = 0; c < CC; ++c) sq = fmaf(wr[CC + c] - wr[c], xcol[c], sq);
    tile[jj][o] = sq;
  }
  __syncthreads();
  for (int it = 0; it < 32; ++it) {
    int r = it * 2 + (t >> 7);
    Q[((size_t)(pt0 + r)) * OO + (t & 127)] = tile[r][t & 127];
  }
}

// ---------------------------------------------------------------------------
// K3: per-o sum & sumsq of h = P[gather] + Q, deterministic block partials.
// ---------------------------------------------------------------------------
__global__ __launch_bounds__(256) void k_stats(const float* __restrict__ P,
                                               const float* __restrict__ Q,
                                               const int* __restrict__ idx,
                                               float* __restrict__ partial) {
  const int t = threadIdx.x;
  const int o = t & 127, half = t >> 7;
  const int bid = (blockIdx.x & 7) * 64 + (blockIdx.x >> 3);
  float s = 0.f, s2 = 0.f;
  for (int it = 0; it < 16; ++it) {
    int pt = bid * 32 + it * 2 + half;
    int b = pt >> 11;
    float qv = Q[(size_t)pt * OO + o];
    const int* ip = idx + (size_t)pt * KK;
#pragma unroll
    for (int k = 0; k < KK; ++k) {
      float v = P[((size_t)((b << 11) + ip[k])) * OO + o] + qv;
      s += v;
      s2 = fmaf(v, v, s2);
    }
  }
  __shared__ float red[512];
  red[t] = s; red[256 + t] = s2;
  __syncthreads();
  if (t < 128) {
    partial[bid * 128 + o]             = red[t] + red[t + 128];
    partial[512 * 128 + bid * 128 + o] = red[256 + t] + red[256 + t + 128];
  }
}

// ---------------------------------------------------------------------------
// K4: finalize BN -> scale/shift per o.
// ---------------------------------------------------------------------------
__global__ __launch_bounds__(256) void k_fin(const float* __restrict__ partial,
                                             const float* __restrict__ gamma,
                                             const float* __restrict__ beta,
                                             float* __restrict__ ss) {
  __shared__ float red[512];
  int t = threadIdx.x;
  int o = t & 127, h = t >> 7;
  float s = 0.f, s2 = 0.f;
  for (int blk = h; blk < 512; blk += 2) {
    s  += partial[blk * 128 + o];
    s2 += partial[512 * 128 + blk * 128 + o];
  }
  red[t] = s; red[256 + t] = s2;
  __syncthreads();
  if (t < 128) {
    float st  = red[t] + red[t + 128];
    float s2t = red[256 + t] + red[256 + t + 128];
    float mean = st * (1.0f / M_TOT);
    float var  = s2t * (1.0f / M_TOT) - mean * mean;
    float rs = 1.0f / sqrtf(var + 1e-5f);
    float scale = gamma[t] * rs;
    ss[t] = scale;
    ss[128 + t] = beta[t] - mean * scale;
  }
}

// ---------------------------------------------------------------------------
// K5: h = P[gather]+Q -> BN affine -> exact GELU -> max over k -> out[b][o][n].
// max_k gelu(y_k) = gelu(ymax) if ymax>0 else max(gelu(ymax), gelu(ymin)).
// ---------------------------------------------------------------------------
__global__ __launch_bounds__(256) void k_out(const float* __restrict__ P,
                                             const float* __restrict__ Q,
                                             const int* __restrict__ idx,
                                             const float* __restrict__ ss,
                                             float* __restrict__ out) {
  __shared__ float tile[64][OO + 1];               // 33KB
  const int t = threadIdx.x;
  const int o = t & 127, half = t >> 7;
  const int bid = (blockIdx.x & 7) * 32 + (blockIdx.x >> 3);
  const float scale = ss[o], shift = ss[128 + o];
  const int pt0 = bid * 64;
  const int b = pt0 >> 11;
  const float inv_sqrt2 = 0.70710678118654752f;
  for (int it = 0; it < 32; ++it) {
    int pl = it * 2 + half;
    int pt = pt0 + pl;
    float qv = Q[(size_t)pt * OO + o];
    const int* ip = idx + (size_t)pt * KK;
    float vmax = -3.0e38f, vmin = 3.0e38f;
#pragma unroll
    for (int k = 0; k < KK; ++k) {
      float v = P[((size_t)((b << 11) + ip[k])) * OO + o] + qv;
      vmax = fmaxf(vmax, v);
      vmin = fminf(vmin, v);
    }
    float ymax, ymin;
    if (scale >= 0.f) { ymax = fmaf(vmax, scale, shift); ymin = fmaf(vmin, scale, shift); }
    else              { ymax = fmaf(vmin, scale, shift); ymin = fmaf(vmax, scale, shift); }
    float g;
    if (ymax > 0.f) {
      g = 0.5f * ymax * (1.0f + erff(ymax * inv_sqrt2));
    } else {
      float g1 = 0.5f * ymax * (1.0f + erff(ymax * inv_sqrt2));
      float g2 = 0.5f * ymin * (1.0f + erff(ymin * inv_sqrt2));
      g = fmaxf(g1, g2);
    }
    tile[pl][o] = g;
  }
  __syncthreads();
  const int n0 = pt0 & (NN - 1);
  for (int rep = 0; rep < 32; ++rep) {
    int oo = rep * 4 + (t >> 6);
    int nn = t & 63;
    out[((size_t)(b * OO + oo) << 11) + n0 + nn] = tile[nn][oo];
  }
}

// ---------------------------------------------------------------------------
extern "C" void kernel_launch(void* const* d_in, const int* in_sizes, int n_in,
                              void* d_out, int out_size, void* d_ws, size_t ws_size,
                              hipStream_t stream) {
  const float* x     = (const float*)d_in[0];
  const float* W     = (const float*)d_in[1];
  const float* gamma = (const float*)d_in[2];
  const float* beta  = (const float*)d_in[3];
  float* out = (float*)d_out;

  double* xx   = (double*)d_ws;                        // 131072 B
  int*    idxp = (int*)(xx + BB * NN);                 // 1310720 B
  float*  P    = (float*)(idxp + (size_t)BB * NN * KK);// 8 MB
  float*  Q    = P + (size_t)BB * NN * OO;             // 8 MB
  float*  part = Q + (size_t)BB * NN * OO;
  float*  ss   = part + 2 * 512 * 128;
  // aliases consumed by k_knn before k_pq writes P/Q:
  ushort* xT   = (ushort*)P;                           // 2 MB
  float*  xTf  = P + (size_t)BB * NN * (CC / 2);       // 4 MB (fp32 rows)
  float*  xxf  = Q;                                    // 64 KB

  const int knn_lds = 32 * NN * 2 + 16 * 64 * 4;       // 135168 B
  hipFuncSetAttribute((const void*)k_knn,
                      hipFuncAttributeMaxDynamicSharedMemorySize, knn_lds);

  hipLaunchKernelGGL(k_prep,  dim3(BB * NN / 256), dim3(256),  0, stream, x, xT, xTf, xx, xxf);
  hipLaunchKernelGGL(k_knn,   dim3(BB * NN / 32),  dim3(1024), knn_lds, stream, xT, xxf, xTf, xx, idxp);
  hipLaunchKernelGGL(k_pq,    dim3(BB * NN / 64),  dim3(256),  0, stream, x, W, P, Q);
  hipLaunchKernelGGL(k_stats, dim3(512),           dim3(256),  0, stream, P, Q, idxp, part);
  hipLaunchKernelGGL(k_fin,   dim3(1),             dim3(256),  0, stream, part, gamma, beta, ss);
  hipLaunchKernelGGL(k_out,   dim3(BB * NN / 64),  dim3(256),  0, stream, P, Q, idxp, ss, out);
}